// Round 4
// baseline (49.560 us; speedup 1.0000x reference)
//
#include <hip/hip_runtime.h>

// Problem constants: B=8, N=2048, M=2048, D=128
#define B_DIM 8
#define N_DIM 2048
#define M_DIM 2048
#define D_DIM 128
#define BM 128
#define BN 128

typedef __bf16 bf16_t;
typedef bf16_t bf16x4 __attribute__((ext_vector_type(4)));
typedef bf16_t bf16x8 __attribute__((ext_vector_type(8)));
typedef float f32x4 __attribute__((ext_vector_type(4)));

// ---------------------------------------------------------------------------
// Kernel 1: fp32 -> bf16 (RNE) + row norms, writing a PRE-FRAGMENTED layout:
// 16B granule index = g*256 + gran*16 + r
//   g    = (global row)/16, r = row & 15, gran = element-chunk (0..15, 8 elems)
// so an MFMA wave fragment load (gran = kk*4 + (lane>>4), r = lane&15) is a
// fully-coalesced 1KB global_load_dwordx4.
// Block = 256 threads = one 16-row group: r = tid&15, gran = tid>>4.
// ---------------------------------------------------------------------------
__global__ __launch_bounds__(256) void prep_kernel(
    const float* __restrict__ L, const float* __restrict__ R,
    bf16x8* __restrict__ LbF, bf16x8* __restrict__ RbF,
    float* __restrict__ nL, float* __restrict__ nR)
{
    __shared__ float part[256];

    const int tid  = threadIdx.x;
    const int r    = tid & 15;
    const int gran = tid >> 4;
    const int grp  = blockIdx.x;              // [0, 1024)  (8*2048/16 row groups)
    const int row  = grp * 16 + r;

    const float* src  = blockIdx.y ? R : L;
    bf16x8*      dstF = blockIdx.y ? RbF : LbF;
    float*       ndst = blockIdx.y ? nR : nL;

    // 8 consecutive floats of this row
    float4 v0 = ((const float4*)src)[(size_t)row * 32 + gran * 2];
    float4 v1 = ((const float4*)src)[(size_t)row * 32 + gran * 2 + 1];
    bf16x8 p = { (bf16_t)v0.x, (bf16_t)v0.y, (bf16_t)v0.z, (bf16_t)v0.w,
                 (bf16_t)v1.x, (bf16_t)v1.y, (bf16_t)v1.z, (bf16_t)v1.w };
    dstF[(size_t)grp * 256 + tid] = p;   // block writes 4KB contiguous

    float s = 0.0f;
    #pragma unroll
    for (int j = 0; j < 8; ++j) {
        float x = (float)p[j];
        s = fmaf(x, x, s);
    }
    part[tid] = s;
    __syncthreads();
    if (tid < 16) {
        float t = 0.0f;
        #pragma unroll
        for (int k = 0; k < 16; ++k) t += part[k * 16 + tid];
        ndst[grp * 16 + tid] = t;
    }
}

// ---------------------------------------------------------------------------
// Kernel 2: LDS-free MFMA distance tile. 128x128 output per block, 4 waves.
// Fragments loaded straight from the pre-fragmented bf16 panels (L2-resident,
// perfectly coalesced). No barriers; occupancy VGPR-bound.
// MFMA operands SWAPPED (mfma(B,A)): out-row = lane&15 (A-row),
// out-col = (lane>>4)*4 + reg (B-row) => float4 stores.
// ---------------------------------------------------------------------------
__global__ __launch_bounds__(256) void dist_mfma_kernel(
    const bf16x8* __restrict__ LbF, const bf16x8* __restrict__ RbF,
    const float* __restrict__ nL, const float* __restrict__ nR,
    float* __restrict__ out)
{
    const int tid  = threadIdx.x;
    const int bx   = blockIdx.x;   // M tile (cols)
    const int by   = blockIdx.y;   // N tile (rows)
    const int bz   = blockIdx.z;   // batch
    const int wid  = tid >> 6;
    const int lane = tid & 63;
    const int lr   = lane & 15;
    const int h    = lane >> 4;    // 0..3

    const int wM = (wid >> 1) * 64;
    const int wN = (wid & 1) * 64;

    // row-group bases (16-row groups): global row = bz*2048 + by*128 + wM + t*16
    const int gA0 = bz * 128 + by * 8 + (wid >> 1) * 4;
    const int gB0 = bz * 128 + bx * 8 + (wid & 1) * 4;

    f32x4 acc[4][4] = {};

    #pragma unroll
    for (int kk = 0; kk < 4; ++kk) {
        bf16x8 af[4], bfr[4];
        const int gidx = (kk * 4 + h) * 16 + lr;
        #pragma unroll
        for (int t = 0; t < 4; ++t) {
            af[t]  = LbF[(size_t)(gA0 + t) * 256 + gidx];
            bfr[t] = RbF[(size_t)(gB0 + t) * 256 + gidx];
        }
        #pragma unroll
        for (int mt = 0; mt < 4; ++mt)
            #pragma unroll
            for (int nt = 0; nt < 4; ++nt)
                acc[mt][nt] = __builtin_amdgcn_mfma_f32_16x16x32_bf16(
                    bfr[nt], af[mt], acc[mt][nt], 0, 0, 0);
    }

    // ---- Epilogue: d2 = l2 + r2 - 2*dot; out = 1/(1+sqrt(max(d2,0)))
    const float* nLb = nL + bz * N_DIM + by * BM;
    const float* nRb = nR + bz * M_DIM + bx * BN;
    const size_t outBase = ((size_t)bz * N_DIM + (size_t)by * BM) * M_DIM + (size_t)bx * BN;

    #pragma unroll
    for (int mt = 0; mt < 4; ++mt) {
        const int row_l = wM + mt * 16 + lr;
        const float l2 = nLb[row_l];
        float* orow = out + outBase + (size_t)row_l * M_DIM;
        #pragma unroll
        for (int nt = 0; nt < 4; ++nt) {
            const int colb = wN + nt * 16 + h * 4;
            f32x4 r2v = *(const f32x4*)&nRb[colb];
            f32x4 a = acc[mt][nt];
            f32x4 o;
            #pragma unroll
            for (int r = 0; r < 4; ++r) {
                float d2 = fmaf(-2.0f, a[r], l2 + r2v[r]);
                d2 = fmaxf(d2, 0.0f);
                float s = __builtin_amdgcn_sqrtf(d2);
                o[r] = __builtin_amdgcn_rcpf(1.0f + s);
            }
            *(f32x4*)(orow + colb) = o;
        }
    }
}

// ---------------------------------------------------------------------------
// Fallback (self-contained, no ws) in case ws_size is too small.
// ---------------------------------------------------------------------------
__device__ inline unsigned short f32_to_bf16_rne(float f) {
    unsigned u = __float_as_uint(f);
    u += 0x7FFFu + ((u >> 16) & 1u);
    return (unsigned short)(u >> 16);
}

__global__ __launch_bounds__(256) void attn_dist_fallback(
    const float* __restrict__ L, const float* __restrict__ R,
    float* __restrict__ out)
{
    __shared__ unsigned short Als[BM * D_DIM];
    __shared__ unsigned short Bls[BN * D_DIM];
    __shared__ float normA[BM];
    __shared__ float normB[BN];

    const int tid = threadIdx.x;
    const int bx = blockIdx.x, by = blockIdx.y, bz = blockIdx.z;

    const float* aSrc = L + ((size_t)bz * N_DIM + (size_t)by * BM) * D_DIM;
    const float* bSrc = R + ((size_t)bz * M_DIM + (size_t)bx * BN) * D_DIM;

    char* AlsB = (char*)Als;
    char* BlsB = (char*)Bls;

    #pragma unroll
    for (int i = 0; i < 16; ++i) {
        int idx = tid + i * 256;
        int row = idx >> 5;
        int c4  = idx & 31;
        float4 va = ((const float4*)aSrc)[idx];
        float4 vb = ((const float4*)bSrc)[idx];
        ushort4 pa, pb;
        pa.x = f32_to_bf16_rne(va.x); pa.y = f32_to_bf16_rne(va.y);
        pa.z = f32_to_bf16_rne(va.z); pa.w = f32_to_bf16_rne(va.w);
        pb.x = f32_to_bf16_rne(vb.x); pb.y = f32_to_bf16_rne(vb.y);
        pb.z = f32_to_bf16_rne(vb.z); pb.w = f32_to_bf16_rne(vb.w);
        int off = row * 256 + c4 * 8;
        off ^= (row & 7) << 4;
        *(ushort4*)(AlsB + off) = pa;
        *(ushort4*)(BlsB + off) = pb;
    }
    __syncthreads();

    {
        int row = tid & 127;
        const char* base = (tid < 128) ? AlsB : BlsB;
        float s = 0.0f;
        #pragma unroll
        for (int c = 0; c < 16; ++c) {
            int off = row * 256 + c * 16;
            off ^= (row & 7) << 4;
            bf16x8 v = *(const bf16x8*)(base + off);
            #pragma unroll
            for (int j = 0; j < 8; ++j) {
                float x = (float)v[j];
                s = fmaf(x, x, s);
            }
        }
        if (tid < 128) normA[row] = s;
        else           normB[row] = s;
    }
    __syncthreads();

    const int wid  = tid >> 6;
    const int lane = tid & 63;
    const int wM = (wid >> 1) * 64;
    const int wN = (wid & 1) * 64;
    const int lr = lane & 15;

    f32x4 acc[4][4] = {};

    #pragma unroll
    for (int kk = 0; kk < 4; ++kk) {
        bf16x8 af[4], bfr[4];
        #pragma unroll
        for (int t = 0; t < 4; ++t) {
            int arow = wM + t * 16 + lr;
            int aoff = arow * 256 + (kk * 32 + (lane >> 4) * 8) * 2;
            aoff ^= (arow & 7) << 4;
            af[t] = *(const bf16x8*)(AlsB + aoff);
            int brow = wN + t * 16 + lr;
            int boff = brow * 256 + (kk * 32 + (lane >> 4) * 8) * 2;
            boff ^= (brow & 7) << 4;
            bfr[t] = *(const bf16x8*)(BlsB + boff);
        }
        #pragma unroll
        for (int mt = 0; mt < 4; ++mt)
            #pragma unroll
            for (int nt = 0; nt < 4; ++nt)
                acc[mt][nt] = __builtin_amdgcn_mfma_f32_16x16x32_bf16(
                    bfr[nt], af[mt], acc[mt][nt], 0, 0, 0);
    }

    const size_t outBase = ((size_t)bz * N_DIM + (size_t)by * BM) * M_DIM + (size_t)bx * BN;
    #pragma unroll
    for (int mt = 0; mt < 4; ++mt) {
        const int row_l = wM + mt * 16 + lr;
        const float l2 = normA[row_l];
        float* orow = out + outBase + (size_t)row_l * M_DIM;
        #pragma unroll
        for (int nt = 0; nt < 4; ++nt) {
            const int colb = wN + nt * 16 + (lane >> 4) * 4;
            f32x4 r2v = *(const f32x4*)&normB[colb];
            f32x4 a = acc[mt][nt];
            f32x4 o;
            #pragma unroll
            for (int r = 0; r < 4; ++r) {
                float d2 = fmaf(-2.0f, a[r], l2 + r2v[r]);
                d2 = fmaxf(d2, 0.0f);
                float s = __builtin_amdgcn_sqrtf(d2);
                o[r] = __builtin_amdgcn_rcpf(1.0f + s);
            }
            *(f32x4*)(orow + colb) = o;
        }
    }
}

extern "C" void kernel_launch(void* const* d_in, const int* in_sizes, int n_in,
                              void* d_out, int out_size, void* d_ws, size_t ws_size,
                              hipStream_t stream) {
    const float* L = (const float*)d_in[0];
    const float* R = (const float*)d_in[1];
    float* out = (float*)d_out;

    const size_t LB_BYTES = (size_t)B_DIM * N_DIM * D_DIM * 2;  // 4 MiB
    const size_t NL_BYTES = (size_t)B_DIM * N_DIM * 4;          // 64 KiB
    const size_t need = 2 * LB_BYTES + 2 * NL_BYTES;

    if (ws_size >= need) {
        char* ws = (char*)d_ws;
        bf16x8* LbF = (bf16x8*)ws;
        bf16x8* RbF = (bf16x8*)(ws + LB_BYTES);
        float*  nLp = (float*)(ws + 2 * LB_BYTES);
        float*  nRp = (float*)(ws + 2 * LB_BYTES + NL_BYTES);

        // 1024 row-groups per matrix (8*2048/16), y: 0=L, 1=R
        prep_kernel<<<dim3(1024, 2, 1), dim3(256), 0, stream>>>(L, R, LbF, RbF, nLp, nRp);
        dist_mfma_kernel<<<dim3(M_DIM / BN, N_DIM / BM, B_DIM), dim3(256), 0, stream>>>(
            LbF, RbF, nLp, nRp, out);
    } else {
        attn_dist_fallback<<<dim3(M_DIM / BN, N_DIM / BM, B_DIM), dim3(256), 0, stream>>>(L, R, out);
    }
}

// Round 5
// 46.237 us; speedup vs baseline: 1.0719x; 1.0719x over previous
//
#include <hip/hip_runtime.h>

// Problem constants: B=8, N=2048, M=2048, D=128
#define B_DIM 8
#define N_DIM 2048
#define M_DIM 2048
#define D_DIM 128
#define BM 128
#define BN 128

typedef __bf16 bf16_t;
typedef bf16_t bf16x4 __attribute__((ext_vector_type(4)));
typedef bf16_t bf16x8 __attribute__((ext_vector_type(8)));
typedef float f32x4 __attribute__((ext_vector_type(4)));

#define GLOAD_LDS16(g, l)                                              \
    __builtin_amdgcn_global_load_lds(                                  \
        (const __attribute__((address_space(1))) void*)(g),            \
        (__attribute__((address_space(3))) void*)(l), 16, 0, 0)

// ---------------------------------------------------------------------------
// Kernel 1: fp32 -> bf16 (RNE) + row norms, writing a PRE-FRAGMENTED layout:
// 16B granule index = g*256 + gran*16 + r
//   g = (global row)/16, r = row & 15, gran = 8-elem chunk (0..15)
// MFMA fragment load (gran = kk*4 + (lane>>4), r = lane&15) is then a fully
// coalesced 1KB load, and a 128-row panel is 32KB contiguous for DMA staging.
// ---------------------------------------------------------------------------
__global__ __launch_bounds__(256) void prep_kernel(
    const float* __restrict__ L, const float* __restrict__ R,
    bf16x8* __restrict__ LbF, bf16x8* __restrict__ RbF,
    float* __restrict__ nL, float* __restrict__ nR)
{
    __shared__ float part[256];

    const int tid  = threadIdx.x;
    const int r    = tid & 15;
    const int gran = tid >> 4;
    const int grp  = blockIdx.x;              // [0, 1024)
    const int row  = grp * 16 + r;

    const float* src  = blockIdx.y ? R : L;
    bf16x8*      dstF = blockIdx.y ? RbF : LbF;
    float*       ndst = blockIdx.y ? nR : nL;

    float4 v0 = ((const float4*)src)[(size_t)row * 32 + gran * 2];
    float4 v1 = ((const float4*)src)[(size_t)row * 32 + gran * 2 + 1];
    bf16x8 p = { (bf16_t)v0.x, (bf16_t)v0.y, (bf16_t)v0.z, (bf16_t)v0.w,
                 (bf16_t)v1.x, (bf16_t)v1.y, (bf16_t)v1.z, (bf16_t)v1.w };
    dstF[(size_t)grp * 256 + tid] = p;

    float s = 0.0f;
    #pragma unroll
    for (int j = 0; j < 8; ++j) {
        float x = (float)p[j];
        s = fmaf(x, x, s);
    }
    part[tid] = s;
    __syncthreads();
    if (tid < 16) {
        float t = 0.0f;
        #pragma unroll
        for (int k = 0; k < 16; ++k) t += part[k * 16 + tid];
        ndst[grp * 16 + tid] = t;
    }
}

// ---------------------------------------------------------------------------
// Kernel 2: hybrid MFMA distance tile. A-panel DMA-staged into linear LDS
// (32 KB, conflict-free contiguous ds_read_b128 fragments); B fragments read
// directly from the pre-fragmented L2-resident global panel. ~33 KB LDS =>
// 4 blocks/CU so store bursts overlap other blocks' stage/MFMA.
// MFMA operands SWAPPED (mfma(B,A)): out-row = lane&15 (A-row),
// out-col = (lane>>4)*4 + reg (B-row) => float4 stores.
// ---------------------------------------------------------------------------
__global__ __launch_bounds__(256, 4) void dist_mfma_kernel(
    const bf16x8* __restrict__ LbF, const bf16x8* __restrict__ RbF,
    const float* __restrict__ nL, const float* __restrict__ nR,
    float* __restrict__ out)
{
    __shared__ bf16x8 Als[2048];   // 32 KB: 8 groups x 256 granules
    __shared__ float nAs[BM];
    __shared__ float nBs[BN];

    const int tid  = threadIdx.x;
    const int bx   = blockIdx.x;   // M tile (cols)
    const int by   = blockIdx.y;   // N tile (rows)
    const int bz   = blockIdx.z;   // batch
    const int wid  = tid >> 6;
    const int lane = tid & 63;
    const int lr   = lane & 15;
    const int h    = lane >> 4;    // 0..3

    // A panel: 8 row-groups starting at bz*128 + by*8, 32KB contiguous
    const bf16x8* aSrc = LbF + (size_t)(bz * 128 + by * 8) * 256;
    char* AlsB = (char*)Als;
    #pragma unroll
    for (int i = 0; i < 8; ++i) {
        int chunk = wid * 8 + i;                     // [0,32): 1KB chunks
        GLOAD_LDS16(aSrc + chunk * 64 + lane, AlsB + chunk * 1024);
    }
    if (tid < 128) nAs[tid] = nL[bz * N_DIM + by * BM + tid];
    else           nBs[tid - 128] = nR[bz * M_DIM + bx * BN + (tid - 128)];
    __syncthreads();

    const int wM = (wid >> 1) * 64;
    const int wN = (wid & 1) * 64;
    const int gB0 = bz * 128 + bx * 8 + (wid & 1) * 4;  // B row-group base
    const int lgA = (wid >> 1) * 4;                     // local A group base

    f32x4 acc[4][4] = {};

    #pragma unroll
    for (int kk = 0; kk < 4; ++kk) {
        const int gidx = (kk * 4 + h) * 16 + lr;
        bf16x8 af[4], bfr[4];
        #pragma unroll
        for (int t = 0; t < 4; ++t) {
            af[t]  = Als[(lgA + t) * 256 + gidx];
            bfr[t] = RbF[(size_t)(gB0 + t) * 256 + gidx];
        }
        #pragma unroll
        for (int mt = 0; mt < 4; ++mt)
            #pragma unroll
            for (int nt = 0; nt < 4; ++nt)
                acc[mt][nt] = __builtin_amdgcn_mfma_f32_16x16x32_bf16(
                    bfr[nt], af[mt], acc[mt][nt], 0, 0, 0);
    }

    // ---- Epilogue: d2 = l2 + r2 - 2*dot; out = 1/(1+sqrt(max(d2,0)))
    const size_t outBase = ((size_t)bz * N_DIM + (size_t)by * BM) * M_DIM + (size_t)bx * BN;
    #pragma unroll
    for (int mt = 0; mt < 4; ++mt) {
        const int row_l = wM + mt * 16 + lr;
        const float l2 = nAs[row_l];
        float* orow = out + outBase + (size_t)row_l * M_DIM;
        #pragma unroll
        for (int nt = 0; nt < 4; ++nt) {
            const int colb = wN + nt * 16 + h * 4;
            f32x4 r2v = *(const f32x4*)&nBs[colb];
            f32x4 a = acc[mt][nt];
            f32x4 o;
            #pragma unroll
            for (int r = 0; r < 4; ++r) {
                float d2 = fmaf(-2.0f, a[r], l2 + r2v[r]);
                d2 = fmaxf(d2, 0.0f);
                float s = __builtin_amdgcn_sqrtf(d2);
                o[r] = __builtin_amdgcn_rcpf(1.0f + s);
            }
            *(f32x4*)(orow + colb) = o;
        }
    }
}

// ---------------------------------------------------------------------------
// Fallback (self-contained, no ws) in case ws_size is too small.
// ---------------------------------------------------------------------------
__device__ inline unsigned short f32_to_bf16_rne(float f) {
    unsigned u = __float_as_uint(f);
    u += 0x7FFFu + ((u >> 16) & 1u);
    return (unsigned short)(u >> 16);
}

__global__ __launch_bounds__(256) void attn_dist_fallback(
    const float* __restrict__ L, const float* __restrict__ R,
    float* __restrict__ out)
{
    __shared__ unsigned short Als[BM * D_DIM];
    __shared__ unsigned short Bls[BN * D_DIM];
    __shared__ float normA[BM];
    __shared__ float normB[BN];

    const int tid = threadIdx.x;
    const int bx = blockIdx.x, by = blockIdx.y, bz = blockIdx.z;

    const float* aSrc = L + ((size_t)bz * N_DIM + (size_t)by * BM) * D_DIM;
    const float* bSrc = R + ((size_t)bz * M_DIM + (size_t)bx * BN) * D_DIM;

    char* AlsB = (char*)Als;
    char* BlsB = (char*)Bls;

    #pragma unroll
    for (int i = 0; i < 16; ++i) {
        int idx = tid + i * 256;
        int row = idx >> 5;
        int c4  = idx & 31;
        float4 va = ((const float4*)aSrc)[idx];
        float4 vb = ((const float4*)bSrc)[idx];
        ushort4 pa, pb;
        pa.x = f32_to_bf16_rne(va.x); pa.y = f32_to_bf16_rne(va.y);
        pa.z = f32_to_bf16_rne(va.z); pa.w = f32_to_bf16_rne(va.w);
        pb.x = f32_to_bf16_rne(vb.x); pb.y = f32_to_bf16_rne(vb.y);
        pb.z = f32_to_bf16_rne(vb.z); pb.w = f32_to_bf16_rne(vb.w);
        int off = row * 256 + c4 * 8;
        off ^= (row & 7) << 4;
        *(ushort4*)(AlsB + off) = pa;
        *(ushort4*)(BlsB + off) = pb;
    }
    __syncthreads();

    {
        int row = tid & 127;
        const char* base = (tid < 128) ? AlsB : BlsB;
        float s = 0.0f;
        #pragma unroll
        for (int c = 0; c < 16; ++c) {
            int off = row * 256 + c * 16;
            off ^= (row & 7) << 4;
            bf16x8 v = *(const bf16x8*)(base + off);
            #pragma unroll
            for (int j = 0; j < 8; ++j) {
                float x = (float)v[j];
                s = fmaf(x, x, s);
            }
        }
        if (tid < 128) normA[row] = s;
        else           normB[row] = s;
    }
    __syncthreads();

    const int wid  = tid >> 6;
    const int lane = tid & 63;
    const int wM = (wid >> 1) * 64;
    const int wN = (wid & 1) * 64;
    const int lr = lane & 15;

    f32x4 acc[4][4] = {};

    #pragma unroll
    for (int kk = 0; kk < 4; ++kk) {
        bf16x8 af[4], bfr[4];
        #pragma unroll
        for (int t = 0; t < 4; ++t) {
            int arow = wM + t * 16 + lr;
            int aoff = arow * 256 + (kk * 32 + (lane >> 4) * 8) * 2;
            aoff ^= (arow & 7) << 4;
            af[t] = *(const bf16x8*)(AlsB + aoff);
            int brow = wN + t * 16 + lr;
            int boff = brow * 256 + (kk * 32 + (lane >> 4) * 8) * 2;
            boff ^= (brow & 7) << 4;
            bfr[t] = *(const bf16x8*)(BlsB + boff);
        }
        #pragma unroll
        for (int mt = 0; mt < 4; ++mt)
            #pragma unroll
            for (int nt = 0; nt < 4; ++nt)
                acc[mt][nt] = __builtin_amdgcn_mfma_f32_16x16x32_bf16(
                    bfr[nt], af[mt], acc[mt][nt], 0, 0, 0);
    }

    const size_t outBase = ((size_t)bz * N_DIM + (size_t)by * BM) * M_DIM + (size_t)bx * BN;
    #pragma unroll
    for (int mt = 0; mt < 4; ++mt) {
        const int row_l = wM + mt * 16 + lr;
        const float l2 = normA[row_l];
        float* orow = out + outBase + (size_t)row_l * M_DIM;
        #pragma unroll
        for (int nt = 0; nt < 4; ++nt) {
            const int colb = wN + nt * 16 + (lane >> 4) * 4;
            f32x4 r2v = *(const f32x4*)&normB[colb];
            f32x4 a = acc[mt][nt];
            f32x4 o;
            #pragma unroll
            for (int r = 0; r < 4; ++r) {
                float d2 = fmaf(-2.0f, a[r], l2 + r2v[r]);
                d2 = fmaxf(d2, 0.0f);
                float s = __builtin_amdgcn_sqrtf(d2);
                o[r] = __builtin_amdgcn_rcpf(1.0f + s);
            }
            *(f32x4*)(orow + colb) = o;
        }
    }
}

extern "C" void kernel_launch(void* const* d_in, const int* in_sizes, int n_in,
                              void* d_out, int out_size, void* d_ws, size_t ws_size,
                              hipStream_t stream) {
    const float* L = (const float*)d_in[0];
    const float* R = (const float*)d_in[1];
    float* out = (float*)d_out;

    const size_t LB_BYTES = (size_t)B_DIM * N_DIM * D_DIM * 2;  // 4 MiB
    const size_t NL_BYTES = (size_t)B_DIM * N_DIM * 4;          // 64 KiB
    const size_t need = 2 * LB_BYTES + 2 * NL_BYTES;

    if (ws_size >= need) {
        char* ws = (char*)d_ws;
        bf16x8* LbF = (bf16x8*)ws;
        bf16x8* RbF = (bf16x8*)(ws + LB_BYTES);
        float*  nLp = (float*)(ws + 2 * LB_BYTES);
        float*  nRp = (float*)(ws + 2 * LB_BYTES + NL_BYTES);

        prep_kernel<<<dim3(1024, 2, 1), dim3(256), 0, stream>>>(L, R, LbF, RbF, nLp, nRp);
        dist_mfma_kernel<<<dim3(M_DIM / BN, N_DIM / BM, B_DIM), dim3(256), 0, stream>>>(
            LbF, RbF, nLp, nRp, out);
    } else {
        attn_dist_fallback<<<dim3(M_DIM / BN, N_DIM / BM, B_DIM), dim3(256), 0, stream>>>(L, R, out);
    }
}